// Round 4
// baseline (389.986 us; speedup 1.0000x reference)
//
#include <hip/hip_runtime.h>

// ============================================================================
// TypeNet triplet embedder: 2x(LSTM + BatchNorm) + FC + L2norm, for a,p,n.
// Round 9 (resubmit — R3 bench was GPUAcquisitionTimeout, no data):
// collapse to 3 kernels + acc2 cross-step pipelining.
//  - prep_all folded into lstm1 prologue: per-WG f32->fp16 B-frag weight
//    convert (Whh1, Wih1, bias; all gate-scaled by -log2e / -2log2e), x staged
//    into a 32KB LDS A-frag tile. No xpad/whhT workspace round-trip.
//  - mid_kernel folded into lstm2 prologue: BN1 scale/shift in LDS, folded
//    into the fp16 W2 fragments during convert; bias2eff = 128-dot per col.
//  - acc2 pipelining (both LSTMs): x-part(t+1)+bias precomputed into the
//    alternate accumulator during cell(t) — matrix pipe is idle there; the
//    post-barrier critical path is ds_read -> h-part MFMA only.
//  - Unconditional xp loads in lstm1 (quad>=1 lanes multiply against zeroed
//    B-frags, so garbage A is harmless) — no exec-mask juggling.
//  - R8 cell kept: 5 exp2 + 2 rcp, pre-scaled gates, absmax 1.95e-3.
// ============================================================================

typedef __attribute__((ext_vector_type(8))) _Float16 half8;
typedef __attribute__((ext_vector_type(4))) float f32x4;

#define TS 128
#define HID 128
#define NGATE 512
#define INV_N (1.0f/65536.0f)   // 1/(B*T)
#define NL2E  -1.4426950408889634f   // -log2(e)
#define N2L2E -2.8853900817779268f   // -2*log2(e)
#define GCLAMP 57.707801635558536f   // 20 * 2*log2(e)

#define BAR() asm volatile("s_waitcnt lgkmcnt(0)\n\ts_barrier" ::: "memory")

__device__ __forceinline__ float rcpf(float x) { return __builtin_amdgcn_rcpf(x); }
__device__ __forceinline__ float ex2(float x) { return __builtin_amdgcn_exp2f(x); }

// Gate pre-activations arrive PRE-SCALED: zi,zf,zo = -log2e*z, zg = -2log2e*z.
__device__ __forceinline__ float lstm_cell(float zi, float zf, float zg, float zo,
                                           float& c) {
  float zgc = __builtin_amdgcn_fmed3f(zg, -GCLAMP, GCLAMP);
  float ei = ex2(zi);
  float ef = ex2(zf);
  float eg = ex2(zgc);
  float eo = ex2(zo);
  float pi = 1.0f + ei, pg = 1.0f + eg, pf = 1.0f + ef;
  float P = pi * pg;
  float rd = rcpf(P * pf);
  float fv = P * rd;                    // sigmoid(zf)
  float ig = (1.0f - eg) * (pf * rd);   // sigmoid(zi)*tanh(zg)
  float cc = fv * c + ig;
  c = cc;
  float t2 = __builtin_amdgcn_fmed3f(cc * N2L2E, -GCLAMP, GCLAMP);
  float ec = ex2(t2);
  float hv = (1.0f - ec) * rcpf((1.0f + eo) * (1.0f + ec));  // sigmoid(zo)*tanh(cc)
  return hv;
}

// A-frag layout for a 16x128 fp16 tile (hb / hs1):
//   addr(row, col) = (col>>5)*512 + ((col>>3)&3)*128 + row*8 + (col&7)
// Reader (MFMA A-frag, row=l15, k=kt*32+quad*8+j): base = kt*512+(quad*16+l15)*8
// => lane-contiguous 16B blocks, conflict-free ds_read_b128.

// ---------------------------------------------------------------------------
// LSTM layer 1 (prep fused). 96 WGs x 512.
// hs1: [96 tile][128 t][2048 halves] A-frag order.
// ---------------------------------------------------------------------------
__global__ __launch_bounds__(512, 2) void lstm1_kernel(
    const float* __restrict__ xa, const float* __restrict__ xpi,
    const float* __restrict__ xn,
    const float* __restrict__ Wih1,      // [512][5]
    const float* __restrict__ bih1, const float* __restrict__ bhh1,
    const float* __restrict__ Whh1,      // [512][128]
    _Float16* __restrict__ hs1,
    float* __restrict__ s1sum, float* __restrict__ s1sq) {
  const int wg = blockIdx.x;             // tile 0..95
  const int inp = wg >> 5;
  const int rloc = (wg & 31) * 16;
  const int tid = threadIdx.x;
  const int w = tid >> 6;                // 0..7
  const int lane = tid & 63;
  const int l15 = lane & 15;
  const int quad = lane >> 4;
  const int col = w * 16 + l15;

  __shared__ _Float16 hb[2][2048];       // double-buffered h, A-frag order, 8 KB
  __shared__ _Float16 xl[16384];         // x A-frags: [128 t][16 r][8 d], 32 KB

  ((half8*)hb)[tid] = (half8){0, 0, 0, 0, 0, 0, 0, 0};
  for (int i = tid; i < 2048; i += 512)
    ((half8*)xl)[i] = (half8){0, 0, 0, 0, 0, 0, 0, 0};
  __syncthreads();                       // zeros visible before scatter-fill

  const float* xg = (inp == 0) ? xa : ((inp == 1) ? xpi : xn);
  for (int i = tid; i < 10240; i += 512) {   // 16 rows x 640 floats, coalesced
    int r = i / 640, cc = i - r * 640;
    int t = cc / 5, d = cc - t * 5;
    xl[(t * 16 + r) * 8 + d] = (_Float16)xg[(size_t)(rloc + r) * 640 + cc];
  }

  const int rbase = (quad * 16 + l15) * 8;
  const int wbase = (w >> 1) * 512 + ((w & 1) * 2 + (l15 >> 3)) * 128 +
                    quad * 32 + (l15 & 7);

  half8 bh[4][4];                        // Whh1 B-frags, gate-scaled fp16
#pragma unroll
  for (int kt = 0; kt < 4; ++kt)
#pragma unroll
    for (int gt = 0; gt < 4; ++gt) {
      int gcol = gt * 128 + col;
      float gs = (gt == 2) ? N2L2E : NL2E;
      const float* ph = Whh1 + (size_t)gcol * HID + kt * 32 + quad * 8;
      f32x4 h0 = *(const f32x4*)ph, h1 = *(const f32x4*)(ph + 4);
      half8 v;
#pragma unroll
      for (int j = 0; j < 4; ++j) {
        v[j] = (_Float16)(h0[j] * gs);
        v[4 + j] = (_Float16)(h1[j] * gs);
      }
      bh[kt][gt] = v;
    }
  half8 bx[4];                           // Wih1, gate-scaled, K=32-padded
#pragma unroll
  for (int gt = 0; gt < 4; ++gt) {
    half8 v = {0, 0, 0, 0, 0, 0, 0, 0};
    if (quad == 0) {
      float gs = (gt == 2) ? N2L2E : NL2E;
#pragma unroll
      for (int j = 0; j < 5; ++j)
        v[j] = (_Float16)(Wih1[(gt * 128 + col) * 5 + j] * gs);
    }
    bx[gt] = v;
  }
  f32x4 biasv[4];
#pragma unroll
  for (int gt = 0; gt < 4; ++gt) {
    int gcol = gt * 128 + col;
    float gs = (gt == 2) ? N2L2E : NL2E;
    float b = (bih1[gcol] + bhh1[gcol]) * gs;
    biasv[gt][0] = b; biasv[gt][1] = b; biasv[gt][2] = b; biasv[gt][3] = b;
  }

  __syncthreads();                       // xl fill visible

  // prologue: acc for t=0 (quad>=1 lanes read x data but bx there is zero)
  half8 xp0 = *(const half8*)&xl[l15 * 8];
  f32x4 accA[4], accB[4];
#pragma unroll
  for (int gt = 0; gt < 4; ++gt)
    accA[gt] = __builtin_amdgcn_mfma_f32_16x16x32_f16(xp0, bx[gt], biasv[gt], 0, 0, 0);

  float c4[4] = {0, 0, 0, 0};
  float ssum = 0.0f, ssq = 0.0f;
  _Float16* hs1w = hs1 + (size_t)wg * TS * 2048;

  auto step = [&](int t, f32x4 (&aC)[4], f32x4 (&aN)[4]) {
    BAR();                               // h(t-1) visible
    half8 ah[4];
#pragma unroll
    for (int kt = 0; kt < 4; ++kt)
      ah[kt] = *(const half8*)&hb[t & 1][kt * 512 + rbase];
    int tn = (t + 1 < TS) ? t + 1 : TS - 1;
    half8 xpn = *(const half8*)&xl[(tn * 16 + l15) * 8];
    if (t > 0) {                         // coalesced h(t-1) -> hs1 (8 B/thread)
      float2 cp = *(const float2*)&hb[t & 1][tid * 4];
      *(float2*)&hs1w[(size_t)(t - 1) * 2048 + tid * 4] = cp;
    }
#pragma unroll
    for (int kt = 0; kt < 4; ++kt)       // h-part into current acc
#pragma unroll
      for (int gt = 0; gt < 4; ++gt)
        aC[gt] = __builtin_amdgcn_mfma_f32_16x16x32_f16(ah[kt], bh[kt][gt], aC[gt], 0, 0, 0);
#pragma unroll
    for (int gt = 0; gt < 4; ++gt)       // x-part(t+1) -> alternate acc (pipe idle)
      aN[gt] = __builtin_amdgcn_mfma_f32_16x16x32_f16(xpn, bx[gt], biasv[gt], 0, 0, 0);
    const int wb = (t + 1) & 1;
    float hv4[4];
#pragma unroll
    for (int r = 0; r < 4; ++r) {
      float hv = lstm_cell(aC[0][r], aC[1][r], aC[2][r], aC[3][r], c4[r]);
      hb[wb][wbase + r * 8] = (_Float16)hv;
      hv4[r] = hv;
    }
#pragma unroll
    for (int r = 0; r < 4; ++r) { ssum += hv4[r]; ssq += hv4[r] * hv4[r]; }
  };

  for (int t = 0; t < TS; t += 2) {
    step(t, accA, accB);
    step(t + 1, accB, accA);
  }
  BAR();                                 // h(127) visible
  {
    float2 cp = *(const float2*)&hb[0][tid * 4];
    *(float2*)&hs1w[(size_t)(TS - 1) * 2048 + tid * 4] = cp;
  }
  float s = ssum, q = ssq;
  s += __shfl_xor(s, 16); s += __shfl_xor(s, 32);
  q += __shfl_xor(q, 16); q += __shfl_xor(q, 32);
  if (quad == 0) {
    atomicAdd(&s1sum[inp * HID + col], s);
    atomicAdd(&s1sq[inp * HID + col], q);
  }
}

// ---------------------------------------------------------------------------
// LSTM layer 2 (mid fused): BN1-fold + input GEMM + recurrence. 96 WGs x 512.
// ---------------------------------------------------------------------------
__global__ __launch_bounds__(512, 2) void lstm2_kernel(
    const _Float16* __restrict__ hs1,    // [96][128][2048] A-frag order
    const float* __restrict__ Whh2,      // [512][128]
    const float* __restrict__ Wih2,      // [512][128]
    const float* __restrict__ bih2, const float* __restrict__ bhh2,
    const float* __restrict__ g1, const float* __restrict__ b1,
    const float* __restrict__ s1sum, const float* __restrict__ s1sq,
    _Float16* __restrict__ h_last,       // [1536][128]
    float* __restrict__ s2sum, float* __restrict__ s2sq) {
  const int wg = blockIdx.x;             // tile 0..95
  const int inp = wg >> 5;
  const int gr0 = wg * 16;
  const int tid = threadIdx.x;
  const int w = tid >> 6;
  const int lane = tid & 63;
  const int l15 = lane & 15;
  const int quad = lane >> 4;
  const int col = w * 16 + l15;

  __shared__ _Float16 hb[2][2048];
  __shared__ float scb[128], shb[128];   // BN1 scale / shift

  ((half8*)hb)[tid] = (half8){0, 0, 0, 0, 0, 0, 0, 0};
  if (tid < 128) {
    float m = s1sum[inp * HID + tid] * INV_N;
    float v = s1sq[inp * HID + tid] * INV_N - m * m;
    float s = g1[tid] * rsqrtf(v + 1e-5f);
    scb[tid] = s;
    shb[tid] = b1[tid] - m * s;
  }
  __syncthreads();

  const int rbase = (quad * 16 + l15) * 8;
  const int wbase = (w >> 1) * 512 + ((w & 1) * 2 + (l15 >> 3)) * 128 +
                    quad * 32 + (l15 & 7);

  half8 bh[4][4], bxw[4][4];             // Whh2 / BN1-folded Wih2, fp16 frags
#pragma unroll
  for (int kt = 0; kt < 4; ++kt)
#pragma unroll
    for (int gt = 0; gt < 4; ++gt) {
      int gcol = gt * 128 + col;
      float gs = (gt == 2) ? N2L2E : NL2E;
      int k0 = kt * 32 + quad * 8;
      const float* ph = Whh2 + (size_t)gcol * HID + k0;
      const float* px = Wih2 + (size_t)gcol * HID + k0;
      f32x4 h0 = *(const f32x4*)ph, h1 = *(const f32x4*)(ph + 4);
      f32x4 x0 = *(const f32x4*)px, x1 = *(const f32x4*)(px + 4);
      half8 vh, vx;
#pragma unroll
      for (int j = 0; j < 4; ++j) {
        vh[j] = (_Float16)(h0[j] * gs);
        vh[4 + j] = (_Float16)(h1[j] * gs);
        vx[j] = (_Float16)(x0[j] * scb[k0 + j] * gs);
        vx[4 + j] = (_Float16)(x1[j] * scb[k0 + 4 + j] * gs);
      }
      bh[kt][gt] = vh;
      bxw[kt][gt] = vx;
    }
  f32x4 biasv[4];                        // bias2eff = b2c + shb . Wih2[gcol,:]
#pragma unroll
  for (int gt = 0; gt < 4; ++gt) {
    int gcol = gt * 128 + col;
    float gs = (gt == 2) ? N2L2E : NL2E;
    float b = bih2[gcol] + bhh2[gcol];
    const float* pr = Wih2 + (size_t)gcol * HID;
    for (int h0 = 0; h0 < HID; h0 += 4) {
      f32x4 wv = *(const f32x4*)&pr[h0];
      b += shb[h0] * wv[0] + shb[h0 + 1] * wv[1] +
           shb[h0 + 2] * wv[2] + shb[h0 + 3] * wv[3];
    }
    b *= gs;
    biasv[gt][0] = b; biasv[gt][1] = b; biasv[gt][2] = b; biasv[gt][3] = b;
  }

  const _Float16* hg = hs1 + (size_t)wg * TS * 2048;
  half8 a2A[4], a2B[4];                  // hs1 A-frag prefetch (t, t+1)
#pragma unroll
  for (int kt = 0; kt < 4; ++kt) {
    a2A[kt] = *(const half8*)&hg[kt * 512 + rbase];
    a2B[kt] = *(const half8*)&hg[(size_t)2048 + kt * 512 + rbase];
  }
  f32x4 accA[4], accB[4];                // prologue: acc for t=0
#pragma unroll
  for (int gt = 0; gt < 4; ++gt)
    accA[gt] = __builtin_amdgcn_mfma_f32_16x16x32_f16(a2A[0], bxw[0][gt], biasv[gt], 0, 0, 0);
#pragma unroll
  for (int kt = 1; kt < 4; ++kt)
#pragma unroll
    for (int gt = 0; gt < 4; ++gt)
      accA[gt] = __builtin_amdgcn_mfma_f32_16x16x32_f16(a2A[kt], bxw[kt][gt], accA[gt], 0, 0, 0);

  float c4[4] = {0, 0, 0, 0};
  float ssum = 0.0f, ssq = 0.0f;

  // fT: prefetch target (frags t+2); fS: x-part source (frags t+1)
  auto step = [&](int t, f32x4 (&aC)[4], f32x4 (&aN)[4],
                  half8 (&fT)[4], half8 (&fS)[4]) {
    BAR();                               // h(t-1) visible; vmcnt untouched
    half8 ah[4];
#pragma unroll
    for (int kt = 0; kt < 4; ++kt)
      ah[kt] = *(const half8*)&hb[t & 1][kt * 512 + rbase];
#pragma unroll
    for (int kt = 0; kt < 4; ++kt)       // h-part into current acc
#pragma unroll
      for (int gt = 0; gt < 4; ++gt)
        aC[gt] = __builtin_amdgcn_mfma_f32_16x16x32_f16(ah[kt], bh[kt][gt], aC[gt], 0, 0, 0);
    if (t + 2 < TS) {                    // global prefetch into dead frag set
#pragma unroll
      for (int kt = 0; kt < 4; ++kt)
        fT[kt] = *(const half8*)&hg[(size_t)(t + 2) * 2048 + kt * 512 + rbase];
    }
#pragma unroll
    for (int gt = 0; gt < 4; ++gt)       // x-part(t+1) -> alternate acc
      aN[gt] = __builtin_amdgcn_mfma_f32_16x16x32_f16(fS[0], bxw[0][gt], biasv[gt], 0, 0, 0);
#pragma unroll
    for (int kt = 1; kt < 4; ++kt)
#pragma unroll
      for (int gt = 0; gt < 4; ++gt)
        aN[gt] = __builtin_amdgcn_mfma_f32_16x16x32_f16(fS[kt], bxw[kt][gt], aN[gt], 0, 0, 0);
    const int wb = (t + 1) & 1;
    float hv4[4];
#pragma unroll
    for (int r = 0; r < 4; ++r) {
      float hv = lstm_cell(aC[0][r], aC[1][r], aC[2][r], aC[3][r], c4[r]);
      hb[wb][wbase + r * 8] = (_Float16)hv;
      hv4[r] = hv;
    }
#pragma unroll
    for (int r = 0; r < 4; ++r) { ssum += hv4[r]; ssq += hv4[r] * hv4[r]; }
  };

  for (int t = 0; t < TS; t += 2) {
    step(t, accA, accB, a2A, a2B);
    step(t + 1, accB, accA, a2B, a2A);
  }

  BAR();                                 // h(127) visible in hb[0]
#pragma unroll
  for (int r = 0; r < 4; ++r)
    h_last[(size_t)(gr0 + quad * 4 + r) * HID + col] = hb[0][wbase + r * 8];

  float s = ssum, q = ssq;
  s += __shfl_xor(s, 16); s += __shfl_xor(s, 32);
  q += __shfl_xor(q, 16); q += __shfl_xor(q, 32);
  if (quad == 0) {
    atomicAdd(&s2sum[inp * HID + col], s);
    atomicAdd(&s2sq[inp * HID + col], q);
  }
}

// ---------------------------------------------------------------------------
// Head: BN2 finalize + FC + L2 normalize. 96 WGs x 16 rows.
// ---------------------------------------------------------------------------
__global__ __launch_bounds__(256, 1) void head_kernel(
    const _Float16* __restrict__ h_last,
    const float* __restrict__ s2sum, const float* __restrict__ s2sq,
    const float* __restrict__ g2, const float* __restrict__ b2,
    const float* __restrict__ fcW, const float* __restrict__ fcb,
    float* __restrict__ out) {
  const int wg = blockIdx.x;
  const int inp = wg >> 5;
  const int gr0 = wg * 16;
  const int tid = threadIdx.x;

  __shared__ float fcwT[128][132];       // fcwT[h][j] = fcW[j][h]
  __shared__ float bnh[16][132];
  __shared__ float s2[128], sh2[128];
  __shared__ float part[16][16];
  __shared__ float inv[16];

  if (tid < 128) {
    float m = s2sum[inp * HID + tid] * INV_N;
    float v = s2sq[inp * HID + tid] * INV_N - m * m;
    float s = g2[tid] * rsqrtf(v + 1e-5f);
    s2[tid] = s; sh2[tid] = b2[tid] - m * s;
  }
  for (int i = tid; i < 16384; i += 256) {
    int j = i >> 7, h = i & 127;
    fcwT[h][j] = fcW[i];
  }
  __syncthreads();
  {
    int row = tid >> 4, c0 = (tid & 15) * 8;
#pragma unroll
    for (int k = 0; k < 8; ++k) {
      int h = c0 + k;
      bnh[row][h] = (float)h_last[(gr0 + row) * HID + h] * s2[h] + sh2[h];
    }
  }
  __syncthreads();
  const int row = tid >> 4, jl = tid & 15;
  float emb[8];
  float sq = 0.0f;
#pragma unroll
  for (int jj = 0; jj < 8; ++jj) {
    int j = jl + jj * 16;
    float acc = fcb[j];
    for (int h = 0; h < HID; ++h) acc += bnh[row][h] * fcwT[h][j];
    emb[jj] = acc; sq += acc * acc;
  }
  part[row][jl] = sq;
  __syncthreads();
  if (tid < 16) {
    float s = 0.0f;
    for (int k = 0; k < 16; ++k) s += part[tid][k];
    float nrm = sqrtf(s);
    inv[tid] = 1.0f / fmaxf(nrm, 1e-12f);
  }
  __syncthreads();
#pragma unroll
  for (int jj = 0; jj < 8; ++jj)
    out[(gr0 + row) * HID + jl + jj * 16] = emb[jj] * inv[row];
}

// ---------------------------------------------------------------------------
extern "C" void kernel_launch(void* const* d_in, const int* in_sizes, int n_in,
                              void* d_out, int out_size, void* d_ws, size_t ws_size,
                              hipStream_t stream) {
  const float* a    = (const float*)d_in[0];
  const float* p    = (const float*)d_in[1];
  const float* nn   = (const float*)d_in[2];
  const float* Wih1 = (const float*)d_in[3];
  const float* Whh1 = (const float*)d_in[4];
  const float* bih1 = (const float*)d_in[5];
  const float* bhh1 = (const float*)d_in[6];
  const float* g1   = (const float*)d_in[7];
  const float* b1   = (const float*)d_in[8];
  const float* Wih2 = (const float*)d_in[9];
  const float* Whh2 = (const float*)d_in[10];
  const float* bih2 = (const float*)d_in[11];
  const float* bhh2 = (const float*)d_in[12];
  const float* g2   = (const float*)d_in[13];
  const float* b2   = (const float*)d_in[14];
  const float* fcW  = (const float*)d_in[15];
  const float* fcb  = (const float*)d_in[16];

  char* ws = (char*)d_ws;
  float* s1sum = (float*)(ws + 0);            // 384 f32
  float* s1sq  = s1sum + 384;
  float* s2sum = s1sum + 768;
  float* s2sq  = s1sum + 1152;                // stats end @6144B
  _Float16* hlast = (_Float16*)(ws + 6144);   // 393216B -> @399360
  _Float16* hs1   = (_Float16*)(ws + 399360); // 50331648B -> ~50.7MB total

  hipMemsetAsync(ws, 0, 6144, stream);  // zero BN stats accumulators

  lstm1_kernel<<<96, 512, 0, stream>>>(a, p, nn, Wih1, bih1, bhh1, Whh1,
                                       hs1, s1sum, s1sq);
  lstm2_kernel<<<96, 512, 0, stream>>>(hs1, Whh2, Wih2, bih2, bhh2, g1, b1,
                                       s1sum, s1sq, hlast, s2sum, s2sq);
  head_kernel<<<96, 256, 0, stream>>>(hlast, s2sum, s2sq, g2, b2, fcW, fcb,
                                      (float*)d_out);
}